// Round 12
// baseline (89.028 us; speedup 1.0000x reference)
//
#include <hip/hip_runtime.h>

#define HWC 16384      // H*W
#define WD  128
#define NC  64
#define EPSV 1e-6f

typedef __attribute__((ext_vector_type(8))) short bf16x8;
typedef __attribute__((ext_vector_type(4))) float f32x4;
typedef __attribute__((ext_vector_type(4))) unsigned int u32x4;

__device__ __forceinline__ unsigned short f2bf(float f) {
  unsigned u = __builtin_bit_cast(unsigned, f);
  u = (u + 0x7FFFu + ((u >> 16) & 1u)) >> 16;   // RNE
  return (unsigned short)u;
}
__device__ __forceinline__ float bfLo(unsigned pk) { return __builtin_bit_cast(float, pk << 16); }
__device__ __forceinline__ float bfHi(unsigned pk) { return __builtin_bit_cast(float, pk & 0xFFFF0000u); }
// XOR swizzle for 128-B-row bf16 tiles.
__device__ __forceinline__ int swz(int row, int colbytes) {
  return ((row << 7) + colbytes) ^ ((row & 7) << 4);
}
__device__ __forceinline__ bf16x8 pack8(float4 a, float4 b) {
  bf16x8 r;
  r[0] = (short)f2bf(a.x); r[1] = (short)f2bf(a.y);
  r[2] = (short)f2bf(a.z); r[3] = (short)f2bf(a.w);
  r[4] = (short)f2bf(b.x); r[5] = (short)f2bf(b.y);
  r[6] = (short)f2bf(b.z); r[7] = (short)f2bf(b.w);
  return r;
}

// Fully fused head->NMF->tail, occupancy-engineered: VGPR<=64, LDS 36 KB,
// 4 blocks/CU (whole grid resident). Row-sequential head staging; taps
// re-read from persistent hl (no reg cache); shfl_xor cross-channel reduce.
__global__ __launch_bounds__(512, 8) void k_fused(const float* __restrict__ x,
                                                  const float* __restrict__ Wh,
                                                  const float* __restrict__ Wt,
                                                  float* __restrict__ out) {
  __shared__ __align__(16) char smem[36864];
  unsigned short* xt = (unsigned short*)smem;            // [80 sites][64 c] bf16 swz, 10240 B (per round)
  unsigned short* hl = (unsigned short*)(smem + 10240);  // [208 sites][64 o] bf16 swz, 26624 B
  unsigned short* uvb = (unsigned short*)smem;           // overlay on xt (dead after head r2)

  const int t = threadIdx.x, lane = t & 63, wv = t >> 6;
  const int bid0 = blockIdx.x;
  const int bid = ((bid0 & 7) << 7) | (bid0 >> 3);  // XCD swizzle, bijective (1024%8==0)
  const int seg = bid & 1, y = (bid >> 1) & 127, b = bid >> 8;
  const int w0 = seg << 6;
  const int l15 = lane & 15, kg = lane >> 4;
  const int mt = wv & 3;
  const int mrow = (mt << 4) + l15;
  const int n0 = (wv >> 2) << 1;

  const int gy0 = y >= 2 ? y - 2 : 0;
  const int gy1 = y;
  const int gy2 = y <= 125 ? y + 2 : 127;
  const int gys[3] = {gy0, gy1, gy2};   // indexed only in unrolled loops

  const float* xb = x + (size_t)b * (NC * HWC);
  const size_t gb = (size_t)b * (NC * HWC) + (size_t)y * WD + w0;

  // ---- head A fragments from global Wh (L2-resident) ----
  bf16x8 ha0, ha1;
  {
    const float* wr = Wh + mrow * 64 + kg * 8;
    ha0 = pack8(*(const float4*)wr, *(const float4*)(wr + 4));
    ha1 = pack8(*(const float4*)(wr + 32), *(const float4*)(wr + 36));
  }

  int colm = w0 - 2 + lane; if (colm < 0) colm = 0;   // main stage col (site=lane)
  const int es = lane & 3, eg = lane >> 2;            // extras (t<32): site 64+es, group eg
  int cole = w0 + 62 + es; if (cole > 127) cole = 127;

  // ================= 3 rounds: stage row r -> head MFMA row r =================
#pragma unroll
  for (int r = 0; r < 3; ++r) {
    { // ---- stage: wave wv loads channels [8wv,+8) at its site ----
      const float* xr = xb + gys[r] * WD + colm;
      bf16x8 v;
#pragma unroll
      for (int u = 0; u < 8; ++u) v[u] = (short)f2bf(xr[(size_t)(wv * 8 + u) * HWC]);
      *(bf16x8*)((char*)xt + swz(lane, wv * 16)) = v;
      if (t < 32) {   // sites 64..67, all 8 groups
        const float* xe = xb + gys[r] * WD + cole;
        bf16x8 ve;
#pragma unroll
        for (int u = 0; u < 8; ++u) ve[u] = (short)f2bf(xe[(size_t)(eg * 8 + u) * HWC]);
        *(bf16x8*)((char*)xt + swz(64 + es, eg * 16)) = ve;
      }
    }
    __syncthreads();
    { // ---- head MFMA: 5 N-tiles x 4 M-tiles over 8 waves; ReLU -> hl ----
      const f32x4 zz = {0.f, 0.f, 0.f, 0.f};
#define HEAD_STEP(NT)                                                              \
      {                                                                            \
        const int s = ((NT) << 4) + l15;                                           \
        const bf16x8 b0 = *(const bf16x8*)((char*)xt + swz(s, kg * 16));           \
        const bf16x8 b1 = *(const bf16x8*)((char*)xt + swz(s, 64 + kg * 16));      \
        f32x4 acc = __builtin_amdgcn_mfma_f32_16x16x32_bf16(ha0, b0, zz, 0, 0, 0); \
        acc = __builtin_amdgcn_mfma_f32_16x16x32_bf16(ha1, b1, acc, 0, 0, 0);      \
        if (s < 68) {                                                              \
          const float v0 = acc[0] > 0.f ? acc[0] : 0.f;                            \
          const float v1 = acc[1] > 0.f ? acc[1] : 0.f;                            \
          const float v2 = acc[2] > 0.f ? acc[2] : 0.f;                            \
          const float v3 = acc[3] > 0.f ? acc[3] : 0.f;                            \
          uint2 pk2;                                                               \
          pk2.x = (unsigned)f2bf(v0) | ((unsigned)f2bf(v1) << 16);                 \
          pk2.y = (unsigned)f2bf(v2) | ((unsigned)f2bf(v3) << 16);                 \
          *(uint2*)((char*)hl + swz(r * 68 + s, (mt * 16 + kg * 4) * 2)) = pk2;    \
        }                                                                          \
      }
      if (wv < 4) { HEAD_STEP(0) HEAD_STEP(2) HEAD_STEP(4) }
      else        { HEAD_STEP(1) HEAD_STEP(3) }
#undef HEAD_STEP
    }
    __syncthreads();
  }

  // ================= NMF: thread = (px, channel-group cg) =================
  const int px = (wv << 3) | (lane >> 3);
  const int cg16 = (lane & 7) << 4;

  // ---- sweep 1: msum per channel + sumk per tap ----
  float msum[8] = {0.f, 0.f, 0.f, 0.f, 0.f, 0.f, 0.f, 0.f};
  float sumk[9];
#pragma unroll
  for (int rk = 0; rk < 9; ++rk) {
    const int rr = rk / 3, kc = rk % 3;
    const u32x4 tp = *(const u32x4*)((char*)hl + swz(rr * 68 + px + 2 * kc, cg16));
    float sk = 0.f;
#pragma unroll
    for (int c = 0; c < 8; ++c) {
      const unsigned w32 = tp[c >> 1];
      const float v = (c & 1) ? bfHi(w32) : bfLo(w32);
      msum[c] += v; sk += v;
    }
    sumk[rk] = sk;
  }
  float mreg[8], S = 0.f;
#pragma unroll
  for (int c = 0; c < 8; ++c) { mreg[c] = msum[c] * (1.f / 9.f); S += mreg[c] * mreg[c]; }

  // ---- sweep 2: A per tap ----
  float A[9];
#pragma unroll
  for (int rk = 0; rk < 9; ++rk) {
    const int rr = rk / 3, kc = rk % 3;
    const u32x4 tp = *(const u32x4*)((char*)hl + swz(rr * 68 + px + 2 * kc, cg16));
    float ak = 0.f;
#pragma unroll
    for (int c = 0; c < 8; ++c) {
      const unsigned w32 = tp[c >> 1];
      const float v = (c & 1) ? bfHi(w32) : bfLo(w32);
      ak += mreg[c] * v;
    }
    A[rk] = ak;
  }

  // ---- butterfly reduce over the 8 channel-group lanes (xor 1,2,4) ----
#pragma unroll
  for (int d = 1; d <= 4; d <<= 1) {
    S += __shfl_xor(S, d);
#pragma unroll
    for (int k = 0; k < 9; ++k) sumk[k] += __shfl_xor(sumk[k], d);
#pragma unroll
    for (int k = 0; k < 9; ++k) A[k] += __shfl_xor(A[k], d);
  }

  float Vk[9], T = 0.f;
#pragma unroll
  for (int k = 0; k < 9; ++k) {
    const float nk = sumk[k] * (1.f / 64.f);
    Vk[k] = nk * (A[k] / (3.f * nk * S + EPSV));
    T += Vk[k] * Vk[k];
  }
  const float V4 = Vk[4];

  // ---- residual loads issue here (latency hides under pass 2) ----
  float resv[2][4];
#pragma unroll
  for (int q = 0; q < 2; ++q)
#pragma unroll
    for (int j = 0; j < 4; ++j)
      resv[q][j] = x[gb + (size_t)(mt * 16 + kg * 4 + j) * HWC + ((n0 + q) << 4) + l15];

  // ---- tail A fragments from global Wt ----
  bf16x8 ta0, ta1;
  {
    const float* wr = Wt + mrow * 64 + kg * 8;
    ta0 = pack8(*(const float4*)wr, *(const float4*)(wr + 4));
    ta1 = pack8(*(const float4*)(wr + 32), *(const float4*)(wr + 36));
  }

  // ---- pass 2: re-read taps, B, U; b128 UV write into uvb (overlay xt) ----
  float Bc[8] = {0.f, 0.f, 0.f, 0.f, 0.f, 0.f, 0.f, 0.f};
#pragma unroll
  for (int rk = 0; rk < 9; ++rk) {
    const int rr = rk / 3, kc = rk % 3;
    const u32x4 tp = *(const u32x4*)((char*)hl + swz(rr * 68 + px + 2 * kc, cg16));
#pragma unroll
    for (int c = 0; c < 8; ++c) {
      const unsigned w32 = tp[c >> 1];
      const float v = (c & 1) ? bfHi(w32) : bfLo(w32);
      Bc[c] += v * Vk[rk];
    }
  }
  {
    bf16x8 vv;
#pragma unroll
    for (int c = 0; c < 8; ++c) {
      const float m = mreg[c];
      const float Uc = m * (Bc[c] / (3.f * m * T + EPSV));
      vv[c] = (short)f2bf(3.f * Uc * V4);
    }
    *(bf16x8*)((char*)uvb + swz(px, cg16)) = vv;   // [px][o]
  }
  __syncthreads();

  // ---- tail MFMA: M-tile mt, N-tiles {n0, n0+1}; + residual ----
  const f32x4 z2 = {0.f, 0.f, 0.f, 0.f};
#pragma unroll
  for (int q = 0; q < 2; ++q) {
    const int pxs = ((n0 + q) << 4) + l15;
    const bf16x8 b0 = *(const bf16x8*)((char*)uvb + swz(pxs, kg * 16));
    const bf16x8 b1 = *(const bf16x8*)((char*)uvb + swz(pxs, 64 + kg * 16));
    f32x4 acc = __builtin_amdgcn_mfma_f32_16x16x32_bf16(ta0, b0, z2, 0, 0, 0);
    acc = __builtin_amdgcn_mfma_f32_16x16x32_bf16(ta1, b1, acc, 0, 0, 0);
#pragma unroll
    for (int j = 0; j < 4; ++j) {
      const int c2 = (mt << 4) + kg * 4 + j;
      const size_t off = gb + (size_t)c2 * HWC + pxs;
      out[off] = acc[j] + resv[q][j];
    }
  }
}

extern "C" void kernel_launch(void* const* d_in, const int* in_sizes, int n_in,
                              void* d_out, int out_size, void* d_ws, size_t ws_size,
                              hipStream_t stream) {
  const float* x  = (const float*)d_in[0];
  const float* Wh = (const float*)d_in[1];
  const float* Wt = (const float*)d_in[2];
  float* out = (float*)d_out;

  k_fused<<<1024, 512, 0, stream>>>(x, Wh, Wt, out);
}

// Round 13
// 29.918 us; speedup vs baseline: 2.9758x; 2.9758x over previous
//
#include <hip/hip_runtime.h>

#define HWC 16384      // H*W
#define WD  128
#define NC  64
#define EPSV 1e-6f

typedef __attribute__((ext_vector_type(8))) short bf16x8;
typedef __attribute__((ext_vector_type(4))) float f32x4;
typedef __attribute__((ext_vector_type(4))) unsigned int u32x4;

__device__ __forceinline__ unsigned short f2bf(float f) {
  unsigned u = __builtin_bit_cast(unsigned, f);
  u = (u + 0x7FFFu + ((u >> 16) & 1u)) >> 16;   // RNE
  return (unsigned short)u;
}
__device__ __forceinline__ float bfLo(unsigned pk) { return __builtin_bit_cast(float, pk << 16); }
__device__ __forceinline__ float bfHi(unsigned pk) { return __builtin_bit_cast(float, pk & 0xFFFF0000u); }
// XOR swizzle for 128-B-row bf16 tiles.
__device__ __forceinline__ int swz(int row, int colbytes) {
  return ((row << 7) + colbytes) ^ ((row & 7) << 4);
}
__device__ __forceinline__ bf16x8 pack8(float4 a, float4 b) {
  bf16x8 r;
  r[0] = (short)f2bf(a.x); r[1] = (short)f2bf(a.y);
  r[2] = (short)f2bf(a.z); r[3] = (short)f2bf(a.w);
  r[4] = (short)f2bf(b.x); r[5] = (short)f2bf(b.y);
  r[6] = (short)f2bf(b.z); r[7] = (short)f2bf(b.w);
  return r;
}

// Fully fused head->NMF->tail. 256 thr = 4 waves, 32-px segment, 2048 blocks.
// LDS 27.6 KB -> ~5 blocks/CU; low register liveness (no tap cache, shfl
// reduce) -> natural VGPR well under 100. 3 barriers.
__global__ __launch_bounds__(256) void k_fused(const float* __restrict__ x,
                                               const float* __restrict__ Wh,
                                               const float* __restrict__ Wt,
                                               float* __restrict__ out) {
  __shared__ __align__(16) char smem[27648];
  unsigned short* xt = (unsigned short*)smem;            // [108 sites][64 c] bf16 swz, 13824 B
  unsigned short* hl = (unsigned short*)(smem + 13824);  // [108 sites][64 o] bf16 swz, 13824 B
  unsigned short* uvb = (unsigned short*)smem;           // overlay on xt (dead after head)

  const int t = threadIdx.x, lane = t & 63, wv = t >> 6;
  const int bid0 = blockIdx.x;
  const int bid = ((bid0 & 7) << 8) | (bid0 >> 3);  // XCD swizzle, bijective (2048%8==0)
  const int seg = bid & 3, y = (bid >> 2) & 127, b = bid >> 9;
  const int w0 = seg << 5;
  const int l15 = lane & 15, kg = lane >> 4;
  const int mt = wv;                    // wave = M-tile
  const int mrow = (mt << 4) + l15;

  const int gy0 = y >= 2 ? y - 2 : 0;
  const int gy1 = y;
  const int gy2 = y <= 125 ? y + 2 : 127;
  const int gys[3] = {gy0, gy1, gy2};   // indexed only in unrolled loops

  const float* xb = x + (size_t)b * (NC * HWC);
  const size_t gb = (size_t)b * (NC * HWC) + (size_t)y * WD + w0;

  // ---- head A fragments from global Wh (L2-resident) ----
  bf16x8 ha0, ha1;
  {
    const float* wr = Wh + mrow * 64 + kg * 8;
    ha0 = pack8(*(const float4*)wr, *(const float4*)(wr + 4));
    ha1 = pack8(*(const float4*)(wr + 32), *(const float4*)(wr + 36));
  }

  // ---- stage xt[site][ch]: site s = r*36+i <-> (row gys[r], col clamp(w0-2+i)) ----
  {
    const int sc_cg = t >> 5, sc_i = t & 31;         // main: i 0..31, all 8 ch-groups
    int colm = w0 - 2 + sc_i; if (colm < 0) colm = 0;
    const int se_cg = t >> 2, se_i = 32 + (t & 3);   // extras (t<32): i 32..35
    int cole = w0 - 2 + se_i; if (cole > 127) cole = 127;
#pragma unroll
    for (int r = 0; r < 3; ++r) {
      const float* xr = xb + gys[r] * WD;
      bf16x8 v;
#pragma unroll
      for (int u = 0; u < 8; ++u) v[u] = (short)f2bf(xr[(size_t)(sc_cg * 8 + u) * HWC + colm]);
      *(bf16x8*)((char*)xt + swz(r * 36 + sc_i, sc_cg * 16)) = v;
      if (t < 32) {
        bf16x8 ve;
#pragma unroll
        for (int u = 0; u < 8; ++u) ve[u] = (short)f2bf(xr[(size_t)(se_cg * 8 + u) * HWC + cole]);
        *(bf16x8*)((char*)xt + swz(r * 36 + se_i, se_cg * 16)) = ve;
      }
    }
  }
  __syncthreads();   // (1)

  // ---- head MFMA: 7 N-tiles x 4 M-tiles (wave = M-tile); ReLU -> hl ----
  {
    const f32x4 zz = {0.f, 0.f, 0.f, 0.f};
#pragma unroll
    for (int nt = 0; nt < 7; ++nt) {
      const int s = (nt << 4) + l15;
      const bf16x8 b0 = *(const bf16x8*)((char*)xt + swz(s, kg * 16));
      const bf16x8 b1 = *(const bf16x8*)((char*)xt + swz(s, 64 + kg * 16));
      f32x4 acc = __builtin_amdgcn_mfma_f32_16x16x32_bf16(ha0, b0, zz, 0, 0, 0);
      acc = __builtin_amdgcn_mfma_f32_16x16x32_bf16(ha1, b1, acc, 0, 0, 0);
      if (s < 108) {
        const float v0 = acc[0] > 0.f ? acc[0] : 0.f;
        const float v1 = acc[1] > 0.f ? acc[1] : 0.f;
        const float v2 = acc[2] > 0.f ? acc[2] : 0.f;
        const float v3 = acc[3] > 0.f ? acc[3] : 0.f;
        uint2 pk2;
        pk2.x = (unsigned)f2bf(v0) | ((unsigned)f2bf(v1) << 16);
        pk2.y = (unsigned)f2bf(v2) | ((unsigned)f2bf(v3) << 16);
        *(uint2*)((char*)hl + swz(s, (mt * 16 + kg * 4) * 2)) = pk2;
      }
    }
  }
  __syncthreads();   // (2)

  // ================= NMF: thread = (px, channel-group cg) =================
  const int px = (wv << 3) | (lane >> 3);   // 0..31
  const int cg16 = (lane & 7) << 4;

  // ---- sweep 1: msum per channel + sumk per tap ----
  float msum[8] = {0.f, 0.f, 0.f, 0.f, 0.f, 0.f, 0.f, 0.f};
  float sumk[9];
#pragma unroll
  for (int rk = 0; rk < 9; ++rk) {
    const int rr = rk / 3, kc = rk % 3;
    const u32x4 tp = *(const u32x4*)((char*)hl + swz(rr * 36 + px + 2 * kc, cg16));
    float sk = 0.f;
#pragma unroll
    for (int c = 0; c < 8; ++c) {
      const unsigned w32 = tp[c >> 1];
      const float v = (c & 1) ? bfHi(w32) : bfLo(w32);
      msum[c] += v; sk += v;
    }
    sumk[rk] = sk;
  }
  float mreg[8], S = 0.f;
#pragma unroll
  for (int c = 0; c < 8; ++c) { mreg[c] = msum[c] * (1.f / 9.f); S += mreg[c] * mreg[c]; }

  // ---- sweep 2: A per tap ----
  float A[9];
#pragma unroll
  for (int rk = 0; rk < 9; ++rk) {
    const int rr = rk / 3, kc = rk % 3;
    const u32x4 tp = *(const u32x4*)((char*)hl + swz(rr * 36 + px + 2 * kc, cg16));
    float ak = 0.f;
#pragma unroll
    for (int c = 0; c < 8; ++c) {
      const unsigned w32 = tp[c >> 1];
      const float v = (c & 1) ? bfHi(w32) : bfLo(w32);
      ak += mreg[c] * v;
    }
    A[rk] = ak;
  }

  // ---- butterfly reduce over the 8 channel-group lanes (xor 1,2,4) ----
#pragma unroll
  for (int d = 1; d <= 4; d <<= 1) {
    S += __shfl_xor(S, d);
#pragma unroll
    for (int k = 0; k < 9; ++k) sumk[k] += __shfl_xor(sumk[k], d);
#pragma unroll
    for (int k = 0; k < 9; ++k) A[k] += __shfl_xor(A[k], d);
  }

  float Vk[9], T = 0.f;
#pragma unroll
  for (int k = 0; k < 9; ++k) {
    const float nk = sumk[k] * (1.f / 64.f);
    Vk[k] = nk * (A[k] / (3.f * nk * S + EPSV));
    T += Vk[k] * Vk[k];
  }
  const float V4 = Vk[4];

  // ---- residual loads issue here (latency hides under pass 2) ----
  float resv[2][4];
#pragma unroll
  for (int q = 0; q < 2; ++q)
#pragma unroll
    for (int j = 0; j < 4; ++j)
      resv[q][j] = x[gb + (size_t)(mt * 16 + kg * 4 + j) * HWC + (q << 4) + l15];

  // ---- tail A fragments from global Wt ----
  bf16x8 ta0, ta1;
  {
    const float* wr = Wt + mrow * 64 + kg * 8;
    ta0 = pack8(*(const float4*)wr, *(const float4*)(wr + 4));
    ta1 = pack8(*(const float4*)(wr + 32), *(const float4*)(wr + 36));
  }

  // ---- pass 2: re-read taps, B, U; b128 UV write into uvb (overlay xt) ----
  float Bc[8] = {0.f, 0.f, 0.f, 0.f, 0.f, 0.f, 0.f, 0.f};
#pragma unroll
  for (int rk = 0; rk < 9; ++rk) {
    const int rr = rk / 3, kc = rk % 3;
    const u32x4 tp = *(const u32x4*)((char*)hl + swz(rr * 36 + px + 2 * kc, cg16));
#pragma unroll
    for (int c = 0; c < 8; ++c) {
      const unsigned w32 = tp[c >> 1];
      const float v = (c & 1) ? bfHi(w32) : bfLo(w32);
      Bc[c] += v * Vk[rk];
    }
  }
  {
    bf16x8 vv;
#pragma unroll
    for (int c = 0; c < 8; ++c) {
      const float m = mreg[c];
      const float Uc = m * (Bc[c] / (3.f * m * T + EPSV));
      vv[c] = (short)f2bf(3.f * Uc * V4);
    }
    *(bf16x8*)((char*)uvb + swz(px, cg16)) = vv;   // [px][o]
  }
  __syncthreads();   // (3)

  // ---- tail MFMA: M-tile mt, N-tiles {0,1}; + residual ----
  const f32x4 z2 = {0.f, 0.f, 0.f, 0.f};
#pragma unroll
  for (int q = 0; q < 2; ++q) {
    const int pxs = (q << 4) + l15;
    const bf16x8 b0 = *(const bf16x8*)((char*)uvb + swz(pxs, kg * 16));
    const bf16x8 b1 = *(const bf16x8*)((char*)uvb + swz(pxs, 64 + kg * 16));
    f32x4 acc = __builtin_amdgcn_mfma_f32_16x16x32_bf16(ta0, b0, z2, 0, 0, 0);
    acc = __builtin_amdgcn_mfma_f32_16x16x32_bf16(ta1, b1, acc, 0, 0, 0);
#pragma unroll
    for (int j = 0; j < 4; ++j) {
      const int c2 = (mt << 4) + kg * 4 + j;
      const size_t off = gb + (size_t)c2 * HWC + pxs;
      out[off] = acc[j] + resv[q][j];
    }
  }
}

extern "C" void kernel_launch(void* const* d_in, const int* in_sizes, int n_in,
                              void* d_out, int out_size, void* d_ws, size_t ws_size,
                              hipStream_t stream) {
  const float* x  = (const float*)d_in[0];
  const float* Wh = (const float*)d_in[1];
  const float* Wt = (const float*)d_in[2];
  float* out = (float*)d_out;

  k_fused<<<2048, 256, 0, stream>>>(x, Wh, Wt, out);
}